// Round 12
// baseline (141.934 us; speedup 1.0000x reference)
//
#include <hip/hip_runtime.h>
#include <stdint.h>

// Problem constants (fixed by the reference)
#define BATCH   4096
#define IN_DIM  1024
#define OUT_DIM 1024

typedef __bf16 bf16x8 __attribute__((ext_vector_type(8)));
typedef float  f32x4  __attribute__((ext_vector_type(4)));

// fp32 -> bf16 bits, round-to-nearest-even
__device__ __forceinline__ uint16_t f2bf(float f) {
    union { float f; uint32_t u; } v; v.f = f;
    uint32_t u = v.u;
    uint32_t r = (u + 0x7FFFu + ((u >> 16) & 1u)) >> 16;
    return (uint16_t)r;
}

__device__ __forceinline__ float bf2f(uint16_t h) {
    union { uint32_t u; float f; } v; v.u = ((uint32_t)h) << 16;
    return v.f;
}

__device__ __forceinline__ ushort4 cvt4(float4 v) {
    ushort4 o;
    o.x = f2bf(v.x); o.y = f2bf(v.y); o.z = f2bf(v.z); o.w = f2bf(v.w);
    return o;
}

// ---------------------------------------------------------------------------
// prep: R11 verified (2048 blocks, 4x work per block).
// ---------------------------------------------------------------------------
__global__ __launch_bounds__(256) void prep(
    const float* __restrict__ x, const float* __restrict__ phase,
    const float* __restrict__ basis, const float* __restrict__ W,
    uint16_t* __restrict__ xb, uint16_t* __restrict__ Wb,
    float* __restrict__ alphaWS)
{
    const int bid = blockIdx.x;
    const int tid = threadIdx.x;

    if (bid < 1024) {
        const int r0 = bid * 4;
        if (tid < 16) {
            const int r = r0 + (tid >> 2), c = tid & 3;
            const float HALF_PI = 1.5707963267948966f;
            float s  = phase[r] / HALF_PI;
            int   q  = (int)floorf(s);
            q = q < 0 ? 0 : (q > 3 ? 3 : q);
            float t  = s - (float)q;
            float t2 = t * t, t3 = t2 * t;
            // CPI[q][k] = (q+k+3)%4  =>  alpha[c] = coef[(c - q + 1) & 3]
            const int j = (c - q + 1) & 3;
            alphaWS[r * 4 + c] = t3 * basis[j] + t2 * basis[4 + j]
                               + t * basis[8 + j] + basis[12 + j];
        }
        const float4* xs = (const float4*)(x + (size_t)r0 * IN_DIM);
        ushort4*      xd = (ushort4*)(xb + (size_t)r0 * IN_DIM);
#pragma unroll
        for (int j = 0; j < 4; ++j)
            xd[j * 256 + tid] = cvt4(xs[j * 256 + tid]);
    } else {
        const size_t j0 = (size_t)(bid - 1024) * 1024;   // of 1M float4s
        const float4* ws = (const float4*)W;
        ushort4*      wd = (ushort4*)Wb;
#pragma unroll
        for (int j = 0; j < 4; ++j)
            wd[j0 + j * 256 + tid] = cvt4(ws[j0 + j * 256 + tid]);
    }
}

// ---------------------------------------------------------------------------
// gemm_fused: R6 skeleton (one block = 64x64 tile, wave wid = control point
// c, in-block c-reduction epilogue) + T4 counted-vmcnt pipeline at BK=32.
//
// Why BK=32: per-K-step buffer = A 64x32 (4KB) + B 4x64x32 (16KB) = 20KB,
// so DOUBLE buffer = 40KB = same LDS as R6 -> occupancy preserved (4
// blocks/CU; R8's 80KB dbuf lost it). Per wave per step: 5 global_load_lds
// (1 A-slice + 4 B_c-slices), 16 MFMA.
//
// Schedule per K-step (loads NEVER drained to 0 in the loop — R8 kept
// __syncthreads whose implicit vmcnt(0) drain was the whole stall):
//   STAGE(next_buf, kt+1)          // 5 loads issued, stay in flight
//   s_waitcnt vmcnt(5)             // waits ONLY for cur's 5 (issued last
//                                  // iter: a full MFMA phase ago -> landed)
//   s_barrier                      // all waves' cur staged
//   sched_barrier(0)               // pin: no ds_read hoist above (rule #18)
//   16 MFMA on cur
//   sched_barrier(0); s_barrier    // all waves' reads of cur done BEFORE
//                                  // anyone stages into it next iteration
// K order (kt*32 ascending) identical to R6's (kt*64, ks*32) -> acc
// accumulation sequence bit-identical.
//
// LDS swizzle (re-derived for 4-chunk rows, same scheme as R0's 8-chunk):
// LDS[row][p] = global[row][p ^ (row&3)]. Staging: slice = 16 rows x 32
// cols = 1KB = one gload_lds; lane l -> row l>>2, phys chunk l&3, source
// chunk (l&3)^((l>>2)&3). Read: phys ch = quad ^ (lane&3); fragment rows
// mi*16+(lane&15) keep row&3 == lane&3.
// ---------------------------------------------------------------------------
#define PS 66   // padded row stride (elems) for epilogue exchange

__global__ __launch_bounds__(256, 4) void gemm_fused(
    const uint16_t* __restrict__ xb, const uint16_t* __restrict__ Wb,
    const float* __restrict__ alphaWS, const float* __restrict__ biases,
    float* __restrict__ out)
{
    __shared__ uint16_t lds[2 * 10240];   // 2 x (A 2048 + B 8192) elems = 40KB
    uint16_t* Ps = lds;                   // epilogue alias [4][64][PS] (33.8KB)

    const int tid  = threadIdx.x;
    const int lane = tid & 63;
    const int wid  = tid >> 6;        // = c for this wave
    const int tileM = blockIdx.x * 64;
    const int tileN = blockIdx.y * 64;

    f32x4 acc[4][4];
#pragma unroll
    for (int mi = 0; mi < 4; ++mi)
#pragma unroll
        for (int ni = 0; ni < 4; ++ni)
            acc[mi][ni] = (f32x4){0.f, 0.f, 0.f, 0.f};

    // staging geometry: slice = 16 rows x 32 cols; lane l -> row l>>2,
    // phys chunk l&3, source global chunk = (l&3) ^ ((l>>2)&3)
    const int srow   = lane >> 2;
    const int gchunk = ((lane & 3) ^ (srow & 3)) * 8;

    const uint16_t* Ag = xb + (size_t)tileM * 1024;
    const uint16_t* Bg = Wb + ((size_t)wid << 20) + (size_t)tileN * 1024;

    const int quad = lane >> 4;
    const int l15  = lane & 15;
    const int ch   = (quad ^ (lane & 3)) * 8;   // read-side phys chunk offset

    // issue this wave's 5 global_load_lds for K-step kt into buffer buf
    auto STAGE = [&](int buf, int kt) {
        const int k0 = kt * 32;
        uint16_t* Asb = lds + buf * 10240;
        uint16_t* Bsb = Asb + 2048;
        // A: 4 slices of 16 rows; wave wid stages slice wid (shared)
        {
            const uint16_t* ga = Ag + (size_t)(wid * 16 + srow) * 1024 + k0 + gchunk;
            __builtin_amdgcn_global_load_lds(
                (const __attribute__((address_space(1))) void*)ga,
                (__attribute__((address_space(3))) void*)(Asb + wid * 512), 16, 0, 0);
        }
        // B_c: own panel, 4 slices
#pragma unroll
        for (int j = 0; j < 4; ++j) {
            const uint16_t* gb = Bg + (size_t)(j * 16 + srow) * 1024 + k0 + gchunk;
            __builtin_amdgcn_global_load_lds(
                (const __attribute__((address_space(1))) void*)gb,
                (__attribute__((address_space(3))) void*)(Bsb + wid * 2048 + j * 512), 16, 0, 0);
        }
    };

    STAGE(0, 0);
    int cur = 0;

    for (int kt = 0; kt < 32; ++kt) {
        if (kt < 31) {
            STAGE(cur ^ 1, kt + 1);                    // next tile in flight
            asm volatile("s_waitcnt vmcnt(5)" ::: "memory");   // cur landed
        } else {
            asm volatile("s_waitcnt vmcnt(0)" ::: "memory");
        }
        __builtin_amdgcn_s_barrier();                  // all waves' cur staged
        __builtin_amdgcn_sched_barrier(0);             // no ds_read hoist

        const uint16_t* Asb = lds + cur * 10240;
        const uint16_t* Bsb = Asb + 2048;

        bf16x8 af[4], bfr[4];
#pragma unroll
        for (int mi = 0; mi < 4; ++mi)
            af[mi] = *(const bf16x8*)(Asb + (mi * 16 + l15) * 32 + ch);
#pragma unroll
        for (int ni = 0; ni < 4; ++ni)
            bfr[ni] = *(const bf16x8*)(Bsb + wid * 2048 + (ni * 16 + l15) * 32 + ch);
#pragma unroll
        for (int mi = 0; mi < 4; ++mi)
#pragma unroll
            for (int ni = 0; ni < 4; ++ni)
                acc[mi][ni] = __builtin_amdgcn_mfma_f32_16x16x32_bf16(
                    af[mi], bfr[ni], acc[mi][ni], 0, 0, 0);

        __builtin_amdgcn_sched_barrier(0);             // no gload sink-above
        __builtin_amdgcn_s_barrier();                  // cur reads done before
        cur ^= 1;                                      // it becomes a target
    }

    // ---- epilogue: in-block c-reduction (R6 verified) ----
    // 1) scale by alpha[m, c=wid] and publish bf16 partials to Ps.
    //    C/D layout: col = lane&15, row(64-tile) = mi*16 + quad*4 + r.
    float av[4][4];
#pragma unroll
    for (int mi = 0; mi < 4; ++mi)
#pragma unroll
        for (int r = 0; r < 4; ++r)
            av[mi][r] = alphaWS[(size_t)(tileM + mi * 16 + quad * 4 + r) * 4 + wid];

#pragma unroll
    for (int mi = 0; mi < 4; ++mi) {
#pragma unroll
        for (int r = 0; r < 4; ++r) {
            const int row = mi * 16 + quad * 4 + r;
#pragma unroll
            for (int ni = 0; ni < 4; ++ni)
                Ps[wid * (64 * PS) + row * PS + ni * 16 + l15] =
                    f2bf(av[mi][r] * acc[mi][ni][r]);
        }
    }
    __syncthreads();

    // 2) combine: thread t -> row rr = t>>2, 16-col group cg = t&3.
    //    out[m,n] = sum_c Ps_c[m,n] + sum_c alpha[m,c]*bias[c,n]
    {
        const int rr = tid >> 2;
        const int cg = tid & 3;
        const int colb = cg * 16;
        const float4 al = *(const float4*)(alphaWS + (size_t)(tileM + rr) * 4);
        const float a[4] = {al.x, al.y, al.z, al.w};

        float res[16];
#pragma unroll
        for (int j = 0; j < 16; ++j) res[j] = 0.f;

#pragma unroll
        for (int cc = 0; cc < 4; ++cc) {
            // alpha-weighted bias (bias is L2-hot, 16KB total)
#pragma unroll
            for (int jj = 0; jj < 4; ++jj) {
                float4 bv = *(const float4*)(biases + (size_t)cc * OUT_DIM + tileN + colb + jj * 4);
                res[jj * 4 + 0] += a[cc] * bv.x;
                res[jj * 4 + 1] += a[cc] * bv.y;
                res[jj * 4 + 2] += a[cc] * bv.z;
                res[jj * 4 + 3] += a[cc] * bv.w;
            }
            // partial (ushort2 = 4B aligned: offsets all even)
            const uint16_t* p = Ps + cc * (64 * PS) + rr * PS + colb;
#pragma unroll
            for (int jj = 0; jj < 8; ++jj) {
                uint32_t pv = *(const uint32_t*)(p + jj * 2);
                res[jj * 2 + 0] += bf2f((uint16_t)(pv & 0xFFFFu));
                res[jj * 2 + 1] += bf2f((uint16_t)(pv >> 16));
            }
        }

        float* orow = out + (size_t)(tileM + rr) * OUT_DIM + tileN + colb;
#pragma unroll
        for (int jj = 0; jj < 4; ++jj) {
            float4 o = {res[jj * 4 + 0], res[jj * 4 + 1], res[jj * 4 + 2], res[jj * 4 + 3]};
            *(float4*)(orow + jj * 4) = o;
        }
    }
}

extern "C" void kernel_launch(void* const* d_in, const int* in_sizes, int n_in,
                              void* d_out, int out_size, void* d_ws, size_t ws_size,
                              hipStream_t stream)
{
    const float* x       = (const float*)d_in[0];  // (B, IN)
    const float* phase   = (const float*)d_in[1];  // (B,)
    const float* weights = (const float*)d_in[2];  // (4, OUT, IN)
    const float* biases  = (const float*)d_in[3];  // (4, OUT)
    const float* basis   = (const float*)d_in[4];  // (4, 4)
    float* out = (float*)d_out;                    // (B, OUT)

    // Workspace: xb bf16 8 MB | Wb bf16 8 MB | alpha 64 KB
    uint16_t* xb = (uint16_t*)d_ws;
    uint16_t* Wb = xb + (size_t)BATCH * IN_DIM;
    float* alphaWS = (float*)(Wb + (size_t)4 * OUT_DIM * IN_DIM);

    prep<<<2048, 256, 0, stream>>>(x, phase, basis, weights, xb, Wb, alphaWS);

    dim3 grid(BATCH / 64, OUT_DIM / 64);   // 1024 blocks, M-fastest for L2
    gemm_fused<<<grid, 256, 0, stream>>>(xb, Wb, alphaWS, biases, out);
}

// Round 13
// 132.093 us; speedup vs baseline: 1.0745x; 1.0745x over previous
//
#include <hip/hip_runtime.h>
#include <stdint.h>

// Problem constants (fixed by the reference)
#define BATCH   4096
#define IN_DIM  1024
#define OUT_DIM 1024

typedef __bf16 bf16x8 __attribute__((ext_vector_type(8)));
typedef float  f32x4  __attribute__((ext_vector_type(4)));

// fp32 -> bf16 bits, round-to-nearest-even
__device__ __forceinline__ uint16_t f2bf(float f) {
    union { float f; uint32_t u; } v; v.f = f;
    uint32_t u = v.u;
    uint32_t r = (u + 0x7FFFu + ((u >> 16) & 1u)) >> 16;
    return (uint16_t)r;
}

__device__ __forceinline__ float bf2f(uint16_t h) {
    union { uint32_t u; float f; } v; v.u = ((uint32_t)h) << 16;
    return v.f;
}

__device__ __forceinline__ ushort4 cvt4(float4 v) {
    ushort4 o;
    o.x = f2bf(v.x); o.y = f2bf(v.y); o.z = f2bf(v.z); o.w = f2bf(v.w);
    return o;
}

// ---------------------------------------------------------------------------
// prep: R11 verified (2048 blocks, 4x work per block).
// ---------------------------------------------------------------------------
__global__ __launch_bounds__(256) void prep(
    const float* __restrict__ x, const float* __restrict__ phase,
    const float* __restrict__ basis, const float* __restrict__ W,
    uint16_t* __restrict__ xb, uint16_t* __restrict__ Wb,
    float* __restrict__ alphaWS)
{
    const int bid = blockIdx.x;
    const int tid = threadIdx.x;

    if (bid < 1024) {
        const int r0 = bid * 4;
        if (tid < 16) {
            const int r = r0 + (tid >> 2), c = tid & 3;
            const float HALF_PI = 1.5707963267948966f;
            float s  = phase[r] / HALF_PI;
            int   q  = (int)floorf(s);
            q = q < 0 ? 0 : (q > 3 ? 3 : q);
            float t  = s - (float)q;
            float t2 = t * t, t3 = t2 * t;
            // CPI[q][k] = (q+k+3)%4  =>  alpha[c] = coef[(c - q + 1) & 3]
            const int j = (c - q + 1) & 3;
            alphaWS[r * 4 + c] = t3 * basis[j] + t2 * basis[4 + j]
                               + t * basis[8 + j] + basis[12 + j];
        }
        const float4* xs = (const float4*)(x + (size_t)r0 * IN_DIM);
        ushort4*      xd = (ushort4*)(xb + (size_t)r0 * IN_DIM);
#pragma unroll
        for (int j = 0; j < 4; ++j)
            xd[j * 256 + tid] = cvt4(xs[j * 256 + tid]);
    } else {
        const size_t j0 = (size_t)(bid - 1024) * 1024;   // of 1M float4s
        const float4* ws = (const float4*)W;
        ushort4*      wd = (ushort4*)Wb;
#pragma unroll
        for (int j = 0; j < 4; ++j)
            wd[j0 + j * 256 + tid] = cvt4(ws[j0 + j * 256 + tid]);
    }
}

// ---------------------------------------------------------------------------
// gemm_fused: R6/R11 kernel VERBATIM (best measured: 46.6-48.7 us) plus ONE
// change: the R9-verified bijective XCD-chunk remap of the tile indices.
//
// Rationale: with default M-fastest dispatch, the 64 consecutive blocks that
// share a B panel round-robin over 8 XCDs -> every XCD L2 re-fetches ~all
// 16MB of Wb. With the remap, hardware XCD j (= lid mod 8) owns nids
// j*128..j*128+127 -> tileN in {2j, 2j+1}: B working set per XCD = 4c x 128
// cols x 2KB = 1MB, fully L2-resident; only A streams. B loads are 8/10 of
// the per-K-step global_load_lds, so this converts the bulk of the exposed
// load latency (the MfmaUtil-28% stall) from L3/HBM (~400-900cy) to L2
// (~200cy).
//
// Main loop / swizzle / epilogue byte-identical to R6 (survived A/B vs
// dbuf-80KB R8, 8-wave R7, B-direct R9, inline-cvt R10, BK=32-vmcnt R12;
// cross-block coherence refuted R2-R5).
// ---------------------------------------------------------------------------
#define PS 66   // padded row stride (elems) for epilogue exchange

__global__ __launch_bounds__(256, 3) void gemm_fused(
    const uint16_t* __restrict__ xb, const uint16_t* __restrict__ Wb,
    const float* __restrict__ alphaWS, const float* __restrict__ biases,
    float* __restrict__ out)
{
    __shared__ uint16_t lds[64 * 64 + 4 * 64 * 64];   // As 8KB | Bs 32KB (40KB)
    uint16_t* As = lds;                                // [64][64]
    uint16_t* Bs = lds + 4096;                         // [4][64][64]
    uint16_t* Ps = lds;                                // epilogue alias [4][64][PS]

    const int tid  = threadIdx.x;
    const int lane = tid & 63;
    const int wid  = tid >> 6;        // = c for this wave

    // XCD-chunked bijective remap (1024 blocks = 8 XCDs x 128):
    // lid mod 8 = hardware XCD -> give it a contiguous nid chunk.
    const int lid = blockIdx.x + (blockIdx.y << 6);
    const int nid = (lid & 7) * 128 + (lid >> 3);
    const int tileM = (nid & 63) * 64;
    const int tileN = (nid >> 6) * 64;

    f32x4 acc[4][4];
#pragma unroll
    for (int mi = 0; mi < 4; ++mi)
#pragma unroll
        for (int ni = 0; ni < 4; ++ni)
            acc[mi][ni] = (f32x4){0.f, 0.f, 0.f, 0.f};

    // staging: slice = 8 rows x 64 cols; lane l -> row l>>3, phys chunk l&7,
    // source global chunk = (l&7) ^ (l>>3)   (XOR swizzle, round-0 verified)
    const int srow = lane >> 3;
    const int gchunk = ((lane & 7) ^ srow) * 8;

    const uint16_t* Ag = xb + (size_t)tileM * 1024;
    const uint16_t* Bg = Wb + ((size_t)wid << 20) + (size_t)tileN * 1024;

    const int quad = lane >> 4;
    const int l7   = lane & 7;

    for (int kt = 0; kt < 16; ++kt) {
        const int k0 = kt * 64;
        // A: 8 slices total, wave stages 2 (shared by all 4 waves)
#pragma unroll
        for (int j = 0; j < 2; ++j) {
            const int s = wid * 2 + j;
            const uint16_t* ga = Ag + (size_t)(s * 8 + srow) * 1024 + k0 + gchunk;
            __builtin_amdgcn_global_load_lds(
                (const __attribute__((address_space(1))) void*)ga,
                (__attribute__((address_space(3))) void*)(As + s * 512), 16, 0, 0);
        }
        // B_c: 8 slices, this wave's own control point
#pragma unroll
        for (int j = 0; j < 8; ++j) {
            const uint16_t* gb = Bg + (size_t)(j * 8 + srow) * 1024 + k0 + gchunk;
            __builtin_amdgcn_global_load_lds(
                (const __attribute__((address_space(1))) void*)gb,
                (__attribute__((address_space(3))) void*)(Bs + wid * 4096 + j * 512), 16, 0, 0);
        }
        __syncthreads();

#pragma unroll
        for (int ks = 0; ks < 2; ++ks) {
            const int ch = (ks * 4 + quad) ^ l7;       // physical chunk
            bf16x8 af[4], bfr[4];
#pragma unroll
            for (int mi = 0; mi < 4; ++mi) {
                const int row = mi * 16 + (lane & 15);
                af[mi] = *(const bf16x8*)(As + row * 64 + ch * 8);
            }
#pragma unroll
            for (int ni = 0; ni < 4; ++ni) {
                const int row = ni * 16 + (lane & 15);
                bfr[ni] = *(const bf16x8*)(Bs + wid * 4096 + row * 64 + ch * 8);
            }
#pragma unroll
            for (int mi = 0; mi < 4; ++mi)
#pragma unroll
                for (int ni = 0; ni < 4; ++ni)
                    acc[mi][ni] = __builtin_amdgcn_mfma_f32_16x16x32_bf16(
                        af[mi], bfr[ni], acc[mi][ni], 0, 0, 0);
        }
        __syncthreads();
    }

    // ---- epilogue: in-block c-reduction ----
    // 1) scale by alpha[m, c=wid] and publish bf16 partials to Ps.
    //    C/D layout: col = lane&15, row(64-tile) = mi*16 + quad*4 + r.
    float av[4][4];
#pragma unroll
    for (int mi = 0; mi < 4; ++mi)
#pragma unroll
        for (int r = 0; r < 4; ++r)
            av[mi][r] = alphaWS[(size_t)(tileM + mi * 16 + quad * 4 + r) * 4 + wid];

#pragma unroll
    for (int mi = 0; mi < 4; ++mi) {
#pragma unroll
        for (int r = 0; r < 4; ++r) {
            const int row = mi * 16 + quad * 4 + r;
#pragma unroll
            for (int ni = 0; ni < 4; ++ni)
                Ps[wid * (64 * PS) + row * PS + ni * 16 + (lane & 15)] =
                    f2bf(av[mi][r] * acc[mi][ni][r]);
        }
    }
    __syncthreads();

    // 2) combine: thread t -> row rr = t>>2, 16-col group cg = t&3.
    //    out[m,n] = sum_c Ps_c[m,n] + sum_c alpha[m,c]*bias[c,n]
    {
        const int rr = tid >> 2;
        const int cg = tid & 3;
        const int colb = cg * 16;
        const float4 al = *(const float4*)(alphaWS + (size_t)(tileM + rr) * 4);
        const float a[4] = {al.x, al.y, al.z, al.w};

        float res[16];
#pragma unroll
        for (int j = 0; j < 16; ++j) res[j] = 0.f;

#pragma unroll
        for (int cc = 0; cc < 4; ++cc) {
            // alpha-weighted bias (bias is L2-hot, 16KB total)
#pragma unroll
            for (int jj = 0; jj < 4; ++jj) {
                float4 bv = *(const float4*)(biases + (size_t)cc * OUT_DIM + tileN + colb + jj * 4);
                res[jj * 4 + 0] += a[cc] * bv.x;
                res[jj * 4 + 1] += a[cc] * bv.y;
                res[jj * 4 + 2] += a[cc] * bv.z;
                res[jj * 4 + 3] += a[cc] * bv.w;
            }
            // partial (ushort2 = 4B aligned: offsets all even)
            const uint16_t* p = Ps + cc * (64 * PS) + rr * PS + colb;
#pragma unroll
            for (int jj = 0; jj < 8; ++jj) {
                uint32_t pv = *(const uint32_t*)(p + jj * 2);
                res[jj * 2 + 0] += bf2f((uint16_t)(pv & 0xFFFFu));
                res[jj * 2 + 1] += bf2f((uint16_t)(pv >> 16));
            }
        }

        float* orow = out + (size_t)(tileM + rr) * OUT_DIM + tileN + colb;
#pragma unroll
        for (int jj = 0; jj < 4; ++jj) {
            float4 o = {res[jj * 4 + 0], res[jj * 4 + 1], res[jj * 4 + 2], res[jj * 4 + 3]};
            *(float4*)(orow + jj * 4) = o;
        }
    }
}

extern "C" void kernel_launch(void* const* d_in, const int* in_sizes, int n_in,
                              void* d_out, int out_size, void* d_ws, size_t ws_size,
                              hipStream_t stream)
{
    const float* x       = (const float*)d_in[0];  // (B, IN)
    const float* phase   = (const float*)d_in[1];  // (B,)
    const float* weights = (const float*)d_in[2];  // (4, OUT, IN)
    const float* biases  = (const float*)d_in[3];  // (4, OUT)
    const float* basis   = (const float*)d_in[4];  // (4, 4)
    float* out = (float*)d_out;                    // (B, OUT)

    // Workspace: xb bf16 8 MB | Wb bf16 8 MB | alpha 64 KB
    uint16_t* xb = (uint16_t*)d_ws;
    uint16_t* Wb = xb + (size_t)BATCH * IN_DIM;
    float* alphaWS = (float*)(Wb + (size_t)4 * OUT_DIM * IN_DIM);

    prep<<<2048, 256, 0, stream>>>(x, phase, basis, weights, xb, Wb, alphaWS);

    dim3 grid(BATCH / 64, OUT_DIM / 64);   // 1024 blocks (remapped in-kernel)
    gemm_fused<<<grid, 256, 0, stream>>>(xb, Wb, alphaWS, biases, out);
}

// Round 14
// 123.462 us; speedup vs baseline: 1.1496x; 1.0699x over previous
//
#include <hip/hip_runtime.h>
#include <stdint.h>

// Problem constants (fixed by the reference)
#define BATCH   4096
#define IN_DIM  1024
#define OUT_DIM 1024

typedef __bf16 bf16x8 __attribute__((ext_vector_type(8)));
typedef float  f32x4  __attribute__((ext_vector_type(4)));

// fp32 -> bf16 bits, round-to-nearest-even
__device__ __forceinline__ uint16_t f2bf(float f) {
    union { float f; uint32_t u; } v; v.f = f;
    uint32_t u = v.u;
    uint32_t r = (u + 0x7FFFu + ((u >> 16) & 1u)) >> 16;
    return (uint16_t)r;
}

__device__ __forceinline__ float bf2f(uint16_t h) {
    union { uint32_t u; float f; } v; v.u = ((uint32_t)h) << 16;
    return v.f;
}

__device__ __forceinline__ ushort4 cvt4(float4 v) {
    ushort4 o;
    o.x = f2bf(v.x); o.y = f2bf(v.y); o.z = f2bf(v.z); o.w = f2bf(v.w);
    return o;
}

// ---------------------------------------------------------------------------
// prep: R11 verified (2048 blocks, 4x work per block).
// ---------------------------------------------------------------------------
__global__ __launch_bounds__(256) void prep(
    const float* __restrict__ x, const float* __restrict__ phase,
    const float* __restrict__ basis, const float* __restrict__ W,
    uint16_t* __restrict__ xb, uint16_t* __restrict__ Wb,
    float* __restrict__ alphaWS)
{
    const int bid = blockIdx.x;
    const int tid = threadIdx.x;

    if (bid < 1024) {
        const int r0 = bid * 4;
        if (tid < 16) {
            const int r = r0 + (tid >> 2), c = tid & 3;
            const float HALF_PI = 1.5707963267948966f;
            float s  = phase[r] / HALF_PI;
            int   q  = (int)floorf(s);
            q = q < 0 ? 0 : (q > 3 ? 3 : q);
            float t  = s - (float)q;
            float t2 = t * t, t3 = t2 * t;
            // CPI[q][k] = (q+k+3)%4  =>  alpha[c] = coef[(c - q + 1) & 3]
            const int j = (c - q + 1) & 3;
            alphaWS[r * 4 + c] = t3 * basis[j] + t2 * basis[4 + j]
                               + t * basis[8 + j] + basis[12 + j];
        }
        const float4* xs = (const float4*)(x + (size_t)r0 * IN_DIM);
        ushort4*      xd = (ushort4*)(xb + (size_t)r0 * IN_DIM);
#pragma unroll
        for (int j = 0; j < 4; ++j)
            xd[j * 256 + tid] = cvt4(xs[j * 256 + tid]);
    } else {
        const size_t j0 = (size_t)(bid - 1024) * 1024;   // of 1M float4s
        const float4* ws = (const float4*)W;
        ushort4*      wd = (ushort4*)Wb;
#pragma unroll
        for (int j = 0; j < 4; ++j)
            wd[j0 + j * 256 + tid] = cvt4(ws[j0 + j * 256 + tid]);
    }
}

// ---------------------------------------------------------------------------
// gemm_fused: L2-staging-bandwidth attack. Counter model: R6/R11 stages
// 640 MB through L2->CU (320 B per MFMA); at ~60 B/cyc/CU that IS the
// observed ~1700-cyc K-step period (dbuf/vmcnt/XCD-remap all null because
// none reduce staged bytes). Fix: 128M x 64N tile, STILL 4 waves / 256
// threads (R7's failure was the 512-thread barrier scope, not the tile).
// Wave wid = c computes the full 128x64 for its control point: 8x4
// fragments, 64 MFMA per K-step per wave. Staged per block-K-step:
// A 16KB (shared x4 waves) + B 32KB (c-private) = 48KB per 256 wave-MFMAs
// = 187 B/MFMA (1.7x better); total staged 393 MB.
// Same verified skeleton: 2 barriers/K-step, XOR-swizzled global_load_lds,
// read chunk (ks*4+quad)^(lane&7); fragment rows keep (lane&15) parity.
// acc[8][4] ~190 VGPR -> launch_bounds(256,2) (no spill; 2 blocks/CU by
// VGPR, LDS 48KB would allow 3).
// Epilogue: R6's verified in-block c-reduction, run twice (one m-half per
// phase) through the same Ps alias.
// ---------------------------------------------------------------------------
#define PS 66   // padded row stride (elems) for epilogue exchange

__global__ __launch_bounds__(256, 2) void gemm_fused(
    const uint16_t* __restrict__ xb, const uint16_t* __restrict__ Wb,
    const float* __restrict__ alphaWS, const float* __restrict__ biases,
    float* __restrict__ out)
{
    __shared__ uint16_t lds[128 * 64 + 4 * 64 * 64];  // As 16KB | Bs 32KB (48KB)
    uint16_t* As = lds;                                // [128][64]
    uint16_t* Bs = lds + 8192;                         // [4][64][64]
    uint16_t* Ps = lds;                                // epilogue alias [4][64][PS]

    const int tid  = threadIdx.x;
    const int lane = tid & 63;
    const int wid  = tid >> 6;        // = c for this wave
    const int tileM = blockIdx.x * 128;
    const int tileN = blockIdx.y * 64;

    f32x4 acc[8][4];
#pragma unroll
    for (int mi = 0; mi < 8; ++mi)
#pragma unroll
        for (int ni = 0; ni < 4; ++ni)
            acc[mi][ni] = (f32x4){0.f, 0.f, 0.f, 0.f};

    // staging: slice = 8 rows x 64 cols; lane l -> row l>>3, phys chunk l&7,
    // source global chunk = (l&7) ^ (l>>3)   (XOR swizzle, round-0 verified)
    const int srow = lane >> 3;
    const int gchunk = ((lane & 7) ^ srow) * 8;

    const uint16_t* Ag = xb + (size_t)tileM * 1024;
    const uint16_t* Bg = Wb + ((size_t)wid << 20) + (size_t)tileN * 1024;

    const int quad = lane >> 4;
    const int l7   = lane & 7;
    const int l15  = lane & 15;

    for (int kt = 0; kt < 16; ++kt) {
        const int k0 = kt * 64;
        // A: 16 slices (128 rows), wave stages 4 — shared by all 4 waves
#pragma unroll
        for (int j = 0; j < 4; ++j) {
            const int s = wid * 4 + j;
            const uint16_t* ga = Ag + (size_t)(s * 8 + srow) * 1024 + k0 + gchunk;
            __builtin_amdgcn_global_load_lds(
                (const __attribute__((address_space(1))) void*)ga,
                (__attribute__((address_space(3))) void*)(As + s * 512), 16, 0, 0);
        }
        // B_c: 8 slices, this wave's own control point
#pragma unroll
        for (int j = 0; j < 8; ++j) {
            const uint16_t* gb = Bg + (size_t)(j * 8 + srow) * 1024 + k0 + gchunk;
            __builtin_amdgcn_global_load_lds(
                (const __attribute__((address_space(1))) void*)gb,
                (__attribute__((address_space(3))) void*)(Bs + wid * 4096 + j * 512), 16, 0, 0);
        }
        __syncthreads();

#pragma unroll
        for (int ks = 0; ks < 2; ++ks) {
            const int ch = (ks * 4 + quad) ^ l7;       // physical chunk
            bf16x8 bfr[4];
#pragma unroll
            for (int ni = 0; ni < 4; ++ni)
                bfr[ni] = *(const bf16x8*)(Bs + wid * 4096 + (ni * 16 + l15) * 64 + ch * 8);
#pragma unroll
            for (int mi = 0; mi < 8; ++mi) {
                bf16x8 af = *(const bf16x8*)(As + (mi * 16 + l15) * 64 + ch * 8);
#pragma unroll
                for (int ni = 0; ni < 4; ++ni)
                    acc[mi][ni] = __builtin_amdgcn_mfma_f32_16x16x32_bf16(
                        af, bfr[ni], acc[mi][ni], 0, 0, 0);
            }
        }
        __syncthreads();
    }

    // ---- epilogue: in-block c-reduction (R6 verified), one m-half per phase ----
    // C/D layout: col = lane&15, row(64-sub-tile) = mi'*16 + quad*4 + r.
#pragma unroll
    for (int p = 0; p < 2; ++p) {
        __syncthreads();               // staging/Ps region quiescent
        // 1) publish alpha-scaled bf16 partials for rows p*64 .. p*64+63
#pragma unroll
        for (int mi = 0; mi < 4; ++mi) {
#pragma unroll
            for (int r = 0; r < 4; ++r) {
                const int row = mi * 16 + quad * 4 + r;
                const float a = alphaWS[(size_t)(tileM + p * 64 + row) * 4 + wid];
#pragma unroll
                for (int ni = 0; ni < 4; ++ni)
                    Ps[wid * (64 * PS) + row * PS + ni * 16 + l15] =
                        f2bf(a * acc[p * 4 + mi][ni][r]);
            }
        }
        __syncthreads();

        // 2) combine: thread t -> row rr = t>>2, 16-col group cg = t&3
        const int rr = tid >> 2;
        const int cg = tid & 3;
        const int colb = cg * 16;
        const int m = tileM + p * 64 + rr;
        const float4 al = *(const float4*)(alphaWS + (size_t)m * 4);
        const float a[4] = {al.x, al.y, al.z, al.w};

        float res[16];
#pragma unroll
        for (int j = 0; j < 16; ++j) res[j] = 0.f;

#pragma unroll
        for (int cc = 0; cc < 4; ++cc) {
            // alpha-weighted bias (bias is L2-hot, 16KB total)
#pragma unroll
            for (int jj = 0; jj < 4; ++jj) {
                float4 bv = *(const float4*)(biases + (size_t)cc * OUT_DIM + tileN + colb + jj * 4);
                res[jj * 4 + 0] += a[cc] * bv.x;
                res[jj * 4 + 1] += a[cc] * bv.y;
                res[jj * 4 + 2] += a[cc] * bv.z;
                res[jj * 4 + 3] += a[cc] * bv.w;
            }
            // partial (ushort2 = 4B aligned: offsets all even)
            const uint16_t* pp = Ps + cc * (64 * PS) + rr * PS + colb;
#pragma unroll
            for (int jj = 0; jj < 8; ++jj) {
                uint32_t pv = *(const uint32_t*)(pp + jj * 2);
                res[jj * 2 + 0] += bf2f((uint16_t)(pv & 0xFFFFu));
                res[jj * 2 + 1] += bf2f((uint16_t)(pv >> 16));
            }
        }

        float* orow = out + (size_t)m * OUT_DIM + tileN + colb;
#pragma unroll
        for (int jj = 0; jj < 4; ++jj) {
            float4 o = {res[jj * 4 + 0], res[jj * 4 + 1], res[jj * 4 + 2], res[jj * 4 + 3]};
            *(float4*)(orow + jj * 4) = o;
        }
    }
}

extern "C" void kernel_launch(void* const* d_in, const int* in_sizes, int n_in,
                              void* d_out, int out_size, void* d_ws, size_t ws_size,
                              hipStream_t stream)
{
    const float* x       = (const float*)d_in[0];  // (B, IN)
    const float* phase   = (const float*)d_in[1];  // (B,)
    const float* weights = (const float*)d_in[2];  // (4, OUT, IN)
    const float* biases  = (const float*)d_in[3];  // (4, OUT)
    const float* basis   = (const float*)d_in[4];  // (4, 4)
    float* out = (float*)d_out;                    // (B, OUT)

    // Workspace: xb bf16 8 MB | Wb bf16 8 MB | alpha 64 KB
    uint16_t* xb = (uint16_t*)d_ws;
    uint16_t* Wb = xb + (size_t)BATCH * IN_DIM;
    float* alphaWS = (float*)(Wb + (size_t)4 * OUT_DIM * IN_DIM);

    prep<<<2048, 256, 0, stream>>>(x, phase, basis, weights, xb, Wb, alphaWS);

    dim3 grid(BATCH / 128, OUT_DIM / 64);  // 512 blocks, M-fastest (default
                                           // order: panel-sharers contemporaneous)
    gemm_fused<<<grid, 256, 0, stream>>>(xb, Wb, alphaWS, biases, out);
}